// Round 2
// baseline (744.483 us; speedup 1.0000x reference)
//
#include <hip/hip_runtime.h>
#include <cstdint>
#include <cmath>

typedef __bf16 bf16;
typedef __bf16 bf16x8 __attribute__((ext_vector_type(8)));
typedef float f32x4 __attribute__((ext_vector_type(4)));

#define B_      2
#define S_      2048
#define H_      16
#define DQK_    128
#define DV_     85
#define DVP_    96
#define DMODEL_ 2048
#define NKV_    1360   // DV*H
#define KP_     1376   // padded K for final gemm (mult of 32)
#define NV_     2720   // DV*H*2
#define NVP_    2816   // padded N for v gemm (mult of 128)
#define SCALE_  0.08838834764831845f

// ---------------- async global->LDS (16B per lane, wave-uniform LDS base) ---
__device__ __forceinline__ void lds_cp16(const void* g, void* l) {
    __builtin_amdgcn_global_load_lds(
        (const __attribute__((address_space(1))) unsigned int*)(uintptr_t)g,
        (__attribute__((address_space(3))) unsigned int*)(uintptr_t)l,
        16, 0, 0);
}

// ---------------- runtime input-dtype detector ------------------------------
// Reads first 256 uint32 words of q. bf16-packed data: low 16 bits are a bf16
// with sane exponent (~all pass). fp32 data: low 16 bits are mantissa noise
// (~15% pass). flag=1 -> inputs are bf16; flag=0 -> inputs are fp32.
__global__ __launch_bounds__(256) void detect_dtype(const unsigned int* __restrict__ w,
                                                    int* __restrict__ flag) {
    __shared__ int cnt;
    if (threadIdx.x == 0) cnt = 0;
    __syncthreads();
    unsigned v = w[threadIdx.x];
    unsigned e = (v >> 7) & 0xFFu;  // exponent field of low-half-as-bf16
    if (e > 100u && e < 140u) atomicAdd(&cnt, 1);
    __syncthreads();
    if (threadIdx.x == 0) *flag = (cnt >= 200) ? 1 : 0;
}

// ---------------- normalize matrix input -> bf16 ---------------------------
__global__ __launch_bounds__(256) void norm_mat(const void* __restrict__ src, bf16* __restrict__ dst,
                                                const int* __restrict__ flag, long n8) {
    long i = (long)blockIdx.x * 256 + threadIdx.x;
    if (i >= n8) return;
    if (*flag) {
        ((bf16x8*)dst)[i] = ((const bf16x8*)src)[i];
    } else {
        const float* s = (const float*)src;
        bf16x8 v;
#pragma unroll
        for (int j = 0; j < 8; ++j) v[j] = (bf16)s[i * 8 + j];
        ((bf16x8*)dst)[i] = v;
    }
}

// ---------------- normalize bias input -> fp32 -----------------------------
__global__ __launch_bounds__(256) void norm_bias(const void* __restrict__ src, float* __restrict__ dst,
                                                 const int* __restrict__ flag, int n) {
    int i = blockIdx.x * 256 + threadIdx.x;
    if (i >= n) return;
    dst[i] = (*flag) ? (float)((const bf16*)src)[i] : ((const float*)src)[i];
}

// ---------------- transpose with zero-padding: out[c][r] = in[r][c] ---------
__global__ __launch_bounds__(256) void transpose_pad(
    const bf16* __restrict__ in, bf16* __restrict__ out,
    int R, int C, int Rp, int Cp) {
    __shared__ bf16 tile[32][33];
    int r0 = blockIdx.x * 32, c0 = blockIdx.y * 32;
    int tx = threadIdx.x, ty = threadIdx.y;
#pragma unroll
    for (int i = 0; i < 32; i += 8) {
        int r = r0 + ty + i, c = c0 + tx;
        tile[ty + i][tx] = (r < R && c < C) ? in[(size_t)r * C + c] : (bf16)0.0f;
    }
    __syncthreads();
#pragma unroll
    for (int i = 0; i < 32; i += 8) {
        int oc = c0 + ty + i, orr = r0 + tx;
        if (oc < Cp && orr < Rp) out[(size_t)oc * Rp + orr] = tile[tx][ty + i];
    }
}

// ---------------- m97-style GEMM: C[M][N] = A[M][K] @ Bt[N][K]^T + bias -----
// outflag==nullptr -> always bf16 store to C.
// outflag!=nullptr -> *outflag=1: bf16 store to C; *outflag=0: fp32 store to Cf.
__global__ __launch_bounds__(256) void gemm_bt(
    const bf16* __restrict__ A, const bf16* __restrict__ Bt,
    const float* __restrict__ bias, bf16* __restrict__ C, float* __restrict__ Cf,
    const int* __restrict__ outflag,
    int M, int N, int K, int Nreal, int ldc) {
    __shared__ bf16 As[128 * 32];
    __shared__ bf16 Bs[128 * 32];
    const int t = threadIdx.x, lane = t & 63, w = t >> 6;
    const int m0 = blockIdx.x * 128, n0 = blockIdx.y * 128;
    const int wm = (w >> 1) * 64, wn = (w & 1) * 64;
    const int fm = lane & 15, quad = lane >> 4, fk = quad * 8;
    const int srow = lane >> 2, scol = (lane & 3) * 8;
    f32x4 acc[4][4] = {};
    for (int k0 = 0; k0 < K; k0 += 32) {
        __syncthreads();
#pragma unroll
        for (int j = 0; j < 2; ++j) {
            int c = j * 4 + w;
            lds_cp16(A + (size_t)(m0 + c * 16 + srow) * K + k0 + scol, &As[c * 512]);
            lds_cp16(Bt + (size_t)(n0 + c * 16 + srow) * K + k0 + scol, &Bs[c * 512]);
        }
        __syncthreads();
        bf16x8 af[4], bfr[4];
#pragma unroll
        for (int i = 0; i < 4; ++i) {
            af[i]  = *(const bf16x8*)&As[(wm + i * 16 + fm) * 32 + fk];
            bfr[i] = *(const bf16x8*)&Bs[(wn + i * 16 + fm) * 32 + fk];
        }
#pragma unroll
        for (int i = 0; i < 4; ++i)
#pragma unroll
            for (int jn = 0; jn < 4; ++jn)
                acc[i][jn] = __builtin_amdgcn_mfma_f32_16x16x32_bf16(af[i], bfr[jn], acc[i][jn], 0, 0, 0);
    }
    bool bf16out = (outflag == nullptr) ? true : (*outflag != 0);
#pragma unroll
    for (int jn = 0; jn < 4; ++jn) {
        int col = n0 + wn + jn * 16 + fm;
        if (col >= Nreal) continue;
        float bv = bias[col];
#pragma unroll
        for (int i = 0; i < 4; ++i) {
            int rowb = m0 + wm + i * 16 + quad * 4;
            if (bf16out) {
#pragma unroll
                for (int r = 0; r < 4; ++r)
                    C[(size_t)(rowb + r) * ldc + col] = (bf16)(acc[i][jn][r] + bv);
            } else {
#pragma unroll
                for (int r = 0; r < 4; ++r)
                    Cf[(size_t)(rowb + r) * ldc + col] = acc[i][jn][r] + bv;
            }
        }
    }
}

// ---------------- RoPE + [B,S,H,128] -> [B,H,S,128] transpose --------------
__global__ __launch_bounds__(256) void rope_tr(const bf16* __restrict__ src, bf16* __restrict__ dst) {
    int idx = blockIdx.x * 256 + threadIdx.x;  // B*S*H*64 threads
    int d = idx & 63;
    int h = (idx >> 6) & 15;
    int s = (idx >> 10) & (S_ - 1);
    int b = idx >> 21;
    const bf16* p = src + ((size_t)(b * S_ + s) * DMODEL_ + h * DQK_);
    float x1 = (float)p[d], x2 = (float)p[d + 64];
    float ang = (float)s * exp2f(-(float)d * (13.287712379549449f / 64.0f));
    float sn, cs;
    sincosf(ang, &sn, &cs);
    bf16* q = dst + ((size_t)(b * H_ + h) * S_ + s) * DQK_;
    q[d]      = (bf16)(x1 * cs - x2 * sn);
    q[d + 64] = (bf16)(x2 * cs + x1 * sn);
}

// ---------------- SwiGLU + transpose to V^T [B,H,96(pad),S] ----------------
__global__ __launch_bounds__(256) void swiglu_tr(const bf16* __restrict__ vp, bf16* __restrict__ vt) {
    int idx = blockIdx.x * 256 + threadIdx.x;  // B*S*1360 threads
    int d2 = idx % NKV_;
    int row = idx / NKV_;
    int h = d2 / DV_;
    int d = d2 - h * DV_;
    int s = row & (S_ - 1);
    int b = row >> 11;
    float a = (float)vp[(size_t)row * NV_ + d2];
    float g = (float)vp[(size_t)row * NV_ + NKV_ + d2];
    float sig = 1.0f / (1.0f + __expf(-g));
    vt[((size_t)(b * H_ + h) * DVP_ + d) * S_ + s] = (bf16)(a * g * sig);
}

// ---------------- flash attention: 1 wave = 16 Q rows ----------------------
__global__ __launch_bounds__(256) void attn(
    const bf16* __restrict__ qt, const bf16* __restrict__ kt,
    const bf16* __restrict__ vt, bf16* __restrict__ o) {
    __shared__ bf16 plds[4][16 * 72];
    const int t = threadIdx.x, lane = t & 63, w = t >> 6;
    const int fm = lane & 15, quad = lane >> 4, fk = quad * 8;
    int bh = blockIdx.x & 31;
    int qg = blockIdx.x >> 5;
    int h = bh & 15, b = bh >> 4;
    int q0 = (qg + w * 32) * 16;

    const bf16* qbase = qt + ((size_t)(b * H_ + h) * S_ + q0 + fm) * DQK_ + fk;
    bf16x8 aq[4];
#pragma unroll
    for (int kb = 0; kb < 4; ++kb) aq[kb] = *(const bf16x8*)(qbase + kb * 32);
    const bf16* kbase = kt + (size_t)(b * H_ + h) * S_ * DQK_;
    const bf16* vbase = vt + (size_t)(b * H_ + h) * DVP_ * S_;

    const float NEG_INF = -__builtin_inff();
    float m_r[4] = {NEG_INF, NEG_INF, NEG_INF, NEG_INF};
    float l_r[4] = {0.f, 0.f, 0.f, 0.f};
    f32x4 oacc[6] = {};
    bf16* pl = &plds[w][0];

    int nkt = (q0 + 16 + 63) >> 6;
    for (int it = 0; it < nkt; ++it) {
        int k0 = it * 64;
        f32x4 sc[4] = {};
#pragma unroll
        for (int nt = 0; nt < 4; ++nt) {
            const bf16* kr = kbase + (size_t)(k0 + nt * 16 + fm) * DQK_ + fk;
#pragma unroll
            for (int kb = 0; kb < 4; ++kb)
                sc[nt] = __builtin_amdgcn_mfma_f32_16x16x32_bf16(aq[kb], *(const bf16x8*)(kr + kb * 32), sc[nt], 0, 0, 0);
        }
#pragma unroll
        for (int nt = 0; nt < 4; ++nt)
#pragma unroll
            for (int r = 0; r < 4; ++r) {
                float sv = sc[nt][r] * SCALE_;
                int col = k0 + nt * 16 + fm;
                int rowq = q0 + quad * 4 + r;
                sc[nt][r] = (col > rowq) ? NEG_INF : sv;
            }
        float alpha[4];
#pragma unroll
        for (int r = 0; r < 4; ++r) {
            float mx = fmaxf(fmaxf(sc[0][r], sc[1][r]), fmaxf(sc[2][r], sc[3][r]));
#pragma unroll
            for (int mm = 1; mm < 16; mm <<= 1) mx = fmaxf(mx, __shfl_xor(mx, mm, 64));
            float nm = fmaxf(m_r[r], mx);
            alpha[r] = (m_r[r] == NEG_INF) ? 0.0f : __expf(m_r[r] - nm);
            m_r[r] = nm;
            float rs = 0.f;
#pragma unroll
            for (int nt = 0; nt < 4; ++nt) {
                float p = (sc[nt][r] == NEG_INF) ? 0.0f : __expf(sc[nt][r] - nm);
                sc[nt][r] = p;
                rs += p;
            }
#pragma unroll
            for (int mm = 1; mm < 16; mm <<= 1) rs += __shfl_xor(rs, mm, 64);
            l_r[r] = l_r[r] * alpha[r] + rs;
        }
#pragma unroll
        for (int n2 = 0; n2 < 6; ++n2)
#pragma unroll
            for (int r = 0; r < 4; ++r) oacc[n2][r] *= alpha[r];
        // P: C-layout regs -> LDS -> A-layout frags (per-wave buffer)
#pragma unroll
        for (int nt = 0; nt < 4; ++nt)
#pragma unroll
            for (int r = 0; r < 4; ++r)
                pl[(quad * 4 + r) * 72 + nt * 16 + fm] = (bf16)sc[nt][r];
        asm volatile("s_waitcnt lgkmcnt(0)" ::: "memory");
        bf16x8 pa0 = *(const bf16x8*)(pl + fm * 72 + fk);
        bf16x8 pa1 = *(const bf16x8*)(pl + fm * 72 + 32 + fk);
#pragma unroll
        for (int n2 = 0; n2 < 6; ++n2) {
            const bf16* vr = vbase + (size_t)(n2 * 16 + fm) * S_ + k0 + fk;
            oacc[n2] = __builtin_amdgcn_mfma_f32_16x16x32_bf16(pa0, *(const bf16x8*)vr, oacc[n2], 0, 0, 0);
            oacc[n2] = __builtin_amdgcn_mfma_f32_16x16x32_bf16(pa1, *(const bf16x8*)(vr + 32), oacc[n2], 0, 0, 0);
        }
    }
    float inv_l[4];
#pragma unroll
    for (int r = 0; r < 4; ++r) inv_l[r] = (l_r[r] > 0.f) ? 1.0f / l_r[r] : 0.0f;
#pragma unroll
    for (int n2 = 0; n2 < 6; ++n2) {
        int col = n2 * 16 + fm;
        if (col < DV_) {
#pragma unroll
            for (int r = 0; r < 4; ++r) {
                size_t orow = (size_t)(b * S_ + q0 + quad * 4 + r);
                o[orow * KP_ + h * DV_ + col] = (bf16)(oacc[n2][r] * inv_l[r]);
            }
        }
    }
}

extern "C" void kernel_launch(void* const* d_in, const int* in_sizes, int n_in,
                              void* d_out, int out_size, void* d_ws, size_t ws_size,
                              hipStream_t stream) {
    const void* qin = d_in[0];
    const void* kin = d_in[1];
    const void* vin = d_in[2];
    // d_in[3] = mask: causal, applied analytically
    const void* Wq = d_in[4];
    const void* bq = d_in[5];
    const void* Wk = d_in[6];
    const void* bk = d_in[7];
    const void* Wv = d_in[8];
    const void* bv = d_in[9];
    const void* Wo = d_in[10];
    const void* bo = d_in[11];

    char* ws = (char*)d_ws;
    size_t off = 0;
    auto alloc = [&](size_t bytes) {
        char* p = ws + off;
        off += ((bytes + 255) & ~(size_t)255);
        return (void*)p;
    };
    bf16* qt   = (bf16*)alloc((size_t)B_ * H_ * S_ * DQK_ * 2);   // 16.8 MB
    bf16* ktp  = (bf16*)alloc((size_t)B_ * H_ * S_ * DQK_ * 2);   // 16.8 MB
    bf16* vtp  = (bf16*)alloc((size_t)B_ * H_ * DVP_ * S_ * 2);   // 12.6 MB
    bf16* ob   = (bf16*)alloc((size_t)B_ * S_ * KP_ * 2);         // 11.3 MB
    bf16* wT   = (bf16*)alloc((size_t)NVP_ * DMODEL_ * 2);        // 11.5 MB
    bf16* proj = (bf16*)alloc((size_t)B_ * S_ * NV_ * 2);         // 22.3 MB
    bf16* scr  = (bf16*)alloc((size_t)B_ * S_ * DMODEL_ * 2);     // 16.8 MB (norm staging)
    float* bqf = (float*)alloc(DMODEL_ * 4);
    float* bkf = (float*)alloc(DMODEL_ * 4);
    float* bvf = (float*)alloc(NV_ * 4);
    float* bof = (float*)alloc(DMODEL_ * 4);
    int*  flag = (int*)alloc(256);
    // total ~108 MB

    dim3 tb(32, 8);
    auto nblk = [](long n8) { return (int)((n8 + 255) / 256); };

    // 0. detect input dtype (1 = bf16-packed, 0 = fp32)
    detect_dtype<<<1, 256, 0, stream>>>((const unsigned int*)qin, flag);

    // biases -> fp32
    norm_bias<<<(DMODEL_ + 255) / 256, 256, 0, stream>>>(bq, bqf, flag, DMODEL_);
    norm_bias<<<(DMODEL_ + 255) / 256, 256, 0, stream>>>(bk, bkf, flag, DMODEL_);
    norm_bias<<<(NV_ + 255) / 256, 256, 0, stream>>>(bv, bvf, flag, NV_);
    norm_bias<<<(DMODEL_ + 255) / 256, 256, 0, stream>>>(bo, bof, flag, DMODEL_);

    // Q path: norm Wq -> scr; scr^T -> wT; norm q -> scr; gemm; rope
    long n8_w = (long)DMODEL_ * DMODEL_ / 8;
    long n8_x = (long)B_ * S_ * DMODEL_ / 8;
    norm_mat<<<nblk(n8_w), 256, 0, stream>>>(Wq, scr, flag, n8_w);
    transpose_pad<<<dim3(DMODEL_ / 32, DMODEL_ / 32), tb, 0, stream>>>(scr, wT, DMODEL_, DMODEL_, DMODEL_, DMODEL_);
    norm_mat<<<nblk(n8_x), 256, 0, stream>>>(qin, scr, flag, n8_x);
    gemm_bt<<<dim3(32, 16), 256, 0, stream>>>(scr, wT, bqf, proj, nullptr, nullptr, 4096, 2048, 2048, 2048, 2048);
    rope_tr<<<(B_ * S_ * H_ * 64) / 256, 256, 0, stream>>>(proj, qt);

    // K path
    norm_mat<<<nblk(n8_w), 256, 0, stream>>>(Wk, scr, flag, n8_w);
    transpose_pad<<<dim3(DMODEL_ / 32, DMODEL_ / 32), tb, 0, stream>>>(scr, wT, DMODEL_, DMODEL_, DMODEL_, DMODEL_);
    norm_mat<<<nblk(n8_x), 256, 0, stream>>>(kin, scr, flag, n8_x);
    gemm_bt<<<dim3(32, 16), 256, 0, stream>>>(scr, wT, bkf, proj, nullptr, nullptr, 4096, 2048, 2048, 2048, 2048);
    rope_tr<<<(B_ * S_ * H_ * 64) / 256, 256, 0, stream>>>(proj, ktp);

    // V path: Wv^T [2048][2720] -> [2816][2048] (N-padded)
    long n8_wv = (long)DMODEL_ * NV_ / 8;
    norm_mat<<<nblk(n8_wv), 256, 0, stream>>>(Wv, scr, flag, n8_wv);
    transpose_pad<<<dim3(DMODEL_ / 32, NVP_ / 32), tb, 0, stream>>>(scr, wT, DMODEL_, NV_, DMODEL_, NVP_);
    norm_mat<<<nblk(n8_x), 256, 0, stream>>>(vin, scr, flag, n8_x);
    gemm_bt<<<dim3(32, NVP_ / 128), 256, 0, stream>>>(scr, wT, bvf, proj, nullptr, nullptr, 4096, NVP_, 2048, NV_, NV_);
    hipMemsetAsync(vtp, 0, (size_t)B_ * H_ * DVP_ * S_ * sizeof(bf16), stream);
    swiglu_tr<<<(B_ * S_ * NKV_) / 256, 256, 0, stream>>>(proj, vtp);

    // attention (ob zero-filled so K-pad cols 1360..1375 are 0)
    hipMemsetAsync(ob, 0, (size_t)B_ * S_ * KP_ * sizeof(bf16), stream);
    attn<<<1024, 256, 0, stream>>>(qt, ktp, vtp, ob);

    // output projection: norm Wo -> scr; scr^T (K-padded) -> wT; dual-dtype store
    long n8_wo = (long)NKV_ * DMODEL_ / 8;
    norm_mat<<<nblk(n8_wo), 256, 0, stream>>>(Wo, scr, flag, n8_wo);
    transpose_pad<<<dim3(KP_ / 32, DMODEL_ / 32), tb, 0, stream>>>(scr, wT, NKV_, DMODEL_, KP_, DMODEL_);
    gemm_bt<<<dim3(32, 16), 256, 0, stream>>>(ob, wT, bof, (bf16*)d_out, (float*)d_out, flag,
                                              4096, 2048, KP_, 2048, 2048);
}

// Round 3
// 675.734 us; speedup vs baseline: 1.1017x; 1.1017x over previous
//
#include <hip/hip_runtime.h>
#include <cstdint>
#include <cmath>

typedef __bf16 bf16;
typedef __bf16 bf16x8 __attribute__((ext_vector_type(8)));
typedef float f32x4 __attribute__((ext_vector_type(4)));

#define B_      2
#define S_      2048
#define H_      16
#define DQK_    128
#define DV_     85
#define DVP_    96
#define DMODEL_ 2048
#define NKV_    1360   // DV*H
#define KP_     1376   // padded K for final gemm (mult of 32)
#define NV_     2720   // DV*H*2
#define NVP_    2816   // padded N for v gemm (mult of 128)
#define SCALE_  0.08838834764831845f

// ---------------- async global->LDS (16B per lane, wave-uniform LDS base) ---
__device__ __forceinline__ void lds_cp16(const void* g, void* l) {
    __builtin_amdgcn_global_load_lds(
        (const __attribute__((address_space(1))) unsigned int*)(uintptr_t)g,
        (__attribute__((address_space(3))) unsigned int*)(uintptr_t)l,
        16, 0, 0);
}

// ---------------- runtime input-dtype detector ------------------------------
__global__ __launch_bounds__(256) void detect_dtype(const unsigned int* __restrict__ w,
                                                    int* __restrict__ flag) {
    __shared__ int cnt;
    if (threadIdx.x == 0) cnt = 0;
    __syncthreads();
    unsigned v = w[threadIdx.x];
    unsigned e = (v >> 7) & 0xFFu;  // exponent field of low-half-as-bf16
    if (e > 100u && e < 140u) atomicAdd(&cnt, 1);
    __syncthreads();
    if (threadIdx.x == 0) *flag = (cnt >= 200) ? 1 : 0;
}

// ---------------- normalize matrix input -> bf16 ---------------------------
__global__ __launch_bounds__(256) void norm_mat(const void* __restrict__ src, bf16* __restrict__ dst,
                                                const int* __restrict__ flag, long n8) {
    long i = (long)blockIdx.x * 256 + threadIdx.x;
    if (i >= n8) return;
    if (*flag) {
        ((bf16x8*)dst)[i] = ((const bf16x8*)src)[i];
    } else {
        const float* s = (const float*)src;
        bf16x8 v;
#pragma unroll
        for (int j = 0; j < 8; ++j) v[j] = (bf16)s[i * 8 + j];
        ((bf16x8*)dst)[i] = v;
    }
}

// ---------------- normalize all 4 biases -> fp32 (one launch) ---------------
__global__ __launch_bounds__(256) void norm_bias4(
    const void* __restrict__ s0, const void* __restrict__ s1,
    const void* __restrict__ s2, const void* __restrict__ s3,
    float* __restrict__ d0, float* __restrict__ d1,
    float* __restrict__ d2, float* __restrict__ d3,
    const int* __restrict__ flag) {
    int j = blockIdx.x * 256 + threadIdx.x;
    const void* s; float* d;
    if (j < DMODEL_) { s = s0; d = d0; }
    else if ((j -= DMODEL_) < DMODEL_) { s = s1; d = d1; }
    else if ((j -= DMODEL_) < NV_) { s = s2; d = d2; }
    else if ((j -= NV_) < DMODEL_) { s = s3; d = d3; }
    else return;
    d[j] = (*flag) ? (float)((const bf16*)s)[j] : ((const float*)s)[j];
}

// ---------------- transpose with zero-padding: out[c][r] = in[r][c] ---------
__global__ __launch_bounds__(256) void transpose_pad(
    const bf16* __restrict__ in, bf16* __restrict__ out,
    int R, int C, int Rp, int Cp) {
    __shared__ bf16 tile[32][33];
    int r0 = blockIdx.x * 32, c0 = blockIdx.y * 32;
    int tx = threadIdx.x, ty = threadIdx.y;
#pragma unroll
    for (int i = 0; i < 32; i += 8) {
        int r = r0 + ty + i, c = c0 + tx;
        tile[ty + i][tx] = (r < R && c < C) ? in[(size_t)r * C + c] : (bf16)0.0f;
    }
    __syncthreads();
#pragma unroll
    for (int i = 0; i < 32; i += 8) {
        int oc = c0 + ty + i, orr = r0 + tx;
        if (oc < Cp && orr < Rp) out[(size_t)oc * Rp + orr] = tile[tx][ty + i];
    }
}

// ---------------- m97-style GEMM: C[M][N] = A[M][K] @ Bt[N][K]^T + bias -----
__global__ __launch_bounds__(256) void gemm_bt(
    const bf16* __restrict__ A, const bf16* __restrict__ Bt,
    const float* __restrict__ bias, bf16* __restrict__ C, float* __restrict__ Cf,
    const int* __restrict__ outflag,
    int M, int N, int K, int Nreal, int ldc) {
    __shared__ bf16 As[128 * 32];
    __shared__ bf16 Bs[128 * 32];
    const int t = threadIdx.x, lane = t & 63, w = t >> 6;
    const int m0 = blockIdx.x * 128, n0 = blockIdx.y * 128;
    const int wm = (w >> 1) * 64, wn = (w & 1) * 64;
    const int fm = lane & 15, quad = lane >> 4, fk = quad * 8;
    const int srow = lane >> 2, scol = (lane & 3) * 8;
    f32x4 acc[4][4] = {};
    for (int k0 = 0; k0 < K; k0 += 32) {
        __syncthreads();
#pragma unroll
        for (int j = 0; j < 2; ++j) {
            int c = j * 4 + w;
            lds_cp16(A + (size_t)(m0 + c * 16 + srow) * K + k0 + scol, &As[c * 512]);
            lds_cp16(Bt + (size_t)(n0 + c * 16 + srow) * K + k0 + scol, &Bs[c * 512]);
        }
        __syncthreads();
        bf16x8 af[4], bfr[4];
#pragma unroll
        for (int i = 0; i < 4; ++i) {
            af[i]  = *(const bf16x8*)&As[(wm + i * 16 + fm) * 32 + fk];
            bfr[i] = *(const bf16x8*)&Bs[(wn + i * 16 + fm) * 32 + fk];
        }
#pragma unroll
        for (int i = 0; i < 4; ++i)
#pragma unroll
            for (int jn = 0; jn < 4; ++jn)
                acc[i][jn] = __builtin_amdgcn_mfma_f32_16x16x32_bf16(af[i], bfr[jn], acc[i][jn], 0, 0, 0);
    }
    bool bf16out = (outflag == nullptr) ? true : (*outflag != 0);
#pragma unroll
    for (int jn = 0; jn < 4; ++jn) {
        int col = n0 + wn + jn * 16 + fm;
        if (col >= Nreal) continue;
        float bv = bias[col];
#pragma unroll
        for (int i = 0; i < 4; ++i) {
            int rowb = m0 + wm + i * 16 + quad * 4;
            if (bf16out) {
#pragma unroll
                for (int r = 0; r < 4; ++r)
                    C[(size_t)(rowb + r) * ldc + col] = (bf16)(acc[i][jn][r] + bv);
            } else {
#pragma unroll
                for (int r = 0; r < 4; ++r)
                    Cf[(size_t)(rowb + r) * ldc + col] = acc[i][jn][r] + bv;
            }
        }
    }
}

// ---------------- RoPE + [B,S,H,128] -> [B,H,S,128] transpose --------------
__global__ __launch_bounds__(256) void rope_tr(const bf16* __restrict__ src, bf16* __restrict__ dst) {
    int idx = blockIdx.x * 256 + threadIdx.x;  // B*S*H*64 threads
    int d = idx & 63;
    int h = (idx >> 6) & 15;
    int s = (idx >> 10) & (S_ - 1);
    int b = idx >> 21;
    const bf16* p = src + ((size_t)(b * S_ + s) * DMODEL_ + h * DQK_);
    float x1 = (float)p[d], x2 = (float)p[d + 64];
    float ang = (float)s * exp2f(-(float)d * (13.287712379549449f / 64.0f));
    float sn, cs;
    sincosf(ang, &sn, &cs);
    bf16* q = dst + ((size_t)(b * H_ + h) * S_ + s) * DQK_;
    q[d]      = (bf16)(x1 * cs - x2 * sn);
    q[d + 64] = (bf16)(x2 * cs + x1 * sn);
}

// ---------------- SwiGLU + transpose to V^T [B,H,96(pad),S] ----------------
__global__ __launch_bounds__(256) void swiglu_tr(const bf16* __restrict__ vp, bf16* __restrict__ vt) {
    int idx = blockIdx.x * 256 + threadIdx.x;  // B*S*1360 threads
    int d2 = idx % NKV_;
    int row = idx / NKV_;
    int h = d2 / DV_;
    int d = d2 - h * DV_;
    int s = row & (S_ - 1);
    int b = row >> 11;
    float a = (float)vp[(size_t)row * NV_ + d2];
    float g = (float)vp[(size_t)row * NV_ + NKV_ + d2];
    float sig = 1.0f / (1.0f + __expf(-g));
    vt[((size_t)(b * H_ + h) * DVP_ + d) * S_ + s] = (bf16)(a * g * sig);
}

// ---------------- V^T pad row 95 := 1.0 (ones column for free row-sums) ----
__global__ __launch_bounds__(256) void ones_row(bf16* __restrict__ vt) {
    int idx = blockIdx.x * 256 + threadIdx.x;  // B*H*S threads
    int bh = idx >> 11, s = idx & (S_ - 1);
    vt[((size_t)bh * DVP_ + 95) * S_ + s] = (bf16)1.0f;
}

// ---------------- flash attention: block = (b,h,64 q-rows), 4 waves --------
// K-tile (64x128) and V^T-tile (96x64) staged in LDS via global_load_lds,
// 16B-chunk XOR swizzle so fragment ds_read_b128s are 2-way-bank (free).
// l comes for free from the ones-column (V^T row 95) through the PV MFMA.
__global__ __launch_bounds__(256) void attn(
    const bf16* __restrict__ qt, const bf16* __restrict__ kt,
    const bf16* __restrict__ vt, bf16* __restrict__ o) {
    __shared__ bf16 Ks[64 * 128];      // chunk(r,c') at r*16+c', c' = c ^ (r&15)
    __shared__ bf16 Vs[96 * 64];       // chunk(r,c') at r*8+c',  c' = c ^ (r&7)
    __shared__ bf16 plds[4][16 * 72];
    const int t = threadIdx.x, lane = t & 63, w = t >> 6;
    const int fm = lane & 15, quad = lane >> 4;
    const int bh = blockIdx.x >> 5, qb = blockIdx.x & 31;  // qb fast -> balanced rounds
    const int h = bh & 15, b = bh >> 4;
    const int q0 = qb * 64 + w * 16;

    const bf16* qbase = qt + ((size_t)(b * H_ + h) * S_ + q0 + fm) * DQK_ + quad * 8;
    bf16x8 aq[4];
#pragma unroll
    for (int kb = 0; kb < 4; ++kb) aq[kb] = *(const bf16x8*)(qbase + kb * 32);
    const bf16* kbase = kt + (size_t)(b * H_ + h) * S_ * DQK_;
    const bf16* vbase = vt + (size_t)(b * H_ + h) * DVP_ * S_;

    const float NEG_INF = -__builtin_inff();
    float m_r[4] = {NEG_INF, NEG_INF, NEG_INF, NEG_INF};
    f32x4 oacc[6] = {};
    bf16* pl = &plds[w][0];

    const int nkt = qb + 1;
    for (int it = 0; it < nkt; ++it) {
        const int k0 = it * 64;
        __syncthreads();
        // stage K: 16 issues total (4/wave), 64 rows x 16 chunks
#pragma unroll
        for (int iw = 0; iw < 4; ++iw) {
            int flat = (w * 4 + iw) * 64 + lane;
            int r = flat >> 4, c = (flat & 15) ^ (r & 15);
            lds_cp16(kbase + (size_t)(k0 + r) * DQK_ + c * 8, &Ks[(w * 4 + iw) * 512]);
        }
        // stage V^T: 12 issues total (3/wave), 96 rows x 8 chunks
#pragma unroll
        for (int iw = 0; iw < 3; ++iw) {
            int flat = (w * 3 + iw) * 64 + lane;
            int r = flat >> 3, c = (flat & 7) ^ (r & 7);
            lds_cp16(vbase + (size_t)r * S_ + k0 + c * 8, &Vs[(w * 3 + iw) * 512]);
        }
        __syncthreads();
        // QK^T (skip wave-uniformly fully-masked nt groups on the diagonal)
        f32x4 sc[4] = {};
#pragma unroll
        for (int nt = 0; nt < 4; ++nt) {
            if (k0 + nt * 16 <= q0 + 15) {
                const int row16 = (nt * 16 + fm) * 16;
#pragma unroll
                for (int kb = 0; kb < 4; ++kb) {
                    const bf16* kp = &Ks[(row16 + ((kb * 4 + quad) ^ fm)) * 8];
                    sc[nt] = __builtin_amdgcn_mfma_f32_16x16x32_bf16(aq[kb], *(const bf16x8*)kp, sc[nt], 0, 0, 0);
                }
            }
        }
        // scale + causal mask
#pragma unroll
        for (int nt = 0; nt < 4; ++nt)
#pragma unroll
            for (int r = 0; r < 4; ++r) {
                float sv = sc[nt][r] * SCALE_;
                int col = k0 + nt * 16 + fm;
                int rowq = q0 + quad * 4 + r;
                sc[nt][r] = (col > rowq) ? NEG_INF : sv;
            }
        // online max + exp (row-sum handled by ones-column in PV)
        float alpha[4];
#pragma unroll
        for (int r = 0; r < 4; ++r) {
            float mx = fmaxf(fmaxf(sc[0][r], sc[1][r]), fmaxf(sc[2][r], sc[3][r]));
#pragma unroll
            for (int mm = 1; mm < 16; mm <<= 1) mx = fmaxf(mx, __shfl_xor(mx, mm, 64));
            float nm = fmaxf(m_r[r], mx);
            alpha[r] = (m_r[r] == NEG_INF) ? 0.0f : __expf(m_r[r] - nm);
            m_r[r] = nm;
#pragma unroll
            for (int nt = 0; nt < 4; ++nt)
                sc[nt][r] = (sc[nt][r] == NEG_INF) ? 0.0f : __expf(sc[nt][r] - nm);
        }
#pragma unroll
        for (int n2 = 0; n2 < 6; ++n2)
#pragma unroll
            for (int r = 0; r < 4; ++r) oacc[n2][r] *= alpha[r];
        // P: C-layout regs -> LDS -> A-layout frags (per-wave buffer)
#pragma unroll
        for (int nt = 0; nt < 4; ++nt)
#pragma unroll
            for (int r = 0; r < 4; ++r)
                pl[(quad * 4 + r) * 72 + nt * 16 + fm] = (bf16)sc[nt][r];
        asm volatile("s_waitcnt lgkmcnt(0)" ::: "memory");
        bf16x8 pa0 = *(const bf16x8*)(pl + fm * 72 + quad * 8);
        bf16x8 pa1 = *(const bf16x8*)(pl + fm * 72 + 32 + quad * 8);
        // PV from LDS V-tile
#pragma unroll
        for (int n2 = 0; n2 < 6; ++n2) {
            int row8 = (n2 * 16 + fm) * 8;
            const bf16* v0 = &Vs[(row8 + (quad ^ (fm & 7))) * 8];
            const bf16* v1 = &Vs[(row8 + ((4 + quad) ^ (fm & 7))) * 8];
            oacc[n2] = __builtin_amdgcn_mfma_f32_16x16x32_bf16(pa0, *(const bf16x8*)v0, oacc[n2], 0, 0, 0);
            oacc[n2] = __builtin_amdgcn_mfma_f32_16x16x32_bf16(pa1, *(const bf16x8*)v1, oacc[n2], 0, 0, 0);
        }
    }
    // l lives in oacc[5] (V^T row 95 == ones) at fm==15 of each quad group
    float inv_l[4];
#pragma unroll
    for (int r = 0; r < 4; ++r) {
        float lv = __shfl(oacc[5][r], (lane & 48) | 15, 64);
        inv_l[r] = (lv > 0.f) ? 1.0f / lv : 0.0f;
    }
#pragma unroll
    for (int n2 = 0; n2 < 6; ++n2) {
        int col = n2 * 16 + fm;
        if (col < DV_) {
#pragma unroll
            for (int r = 0; r < 4; ++r) {
                size_t orow = (size_t)(b * S_ + q0 + quad * 4 + r);
                o[orow * KP_ + h * DV_ + col] = (bf16)(oacc[n2][r] * inv_l[r]);
            }
        }
    }
}

extern "C" void kernel_launch(void* const* d_in, const int* in_sizes, int n_in,
                              void* d_out, int out_size, void* d_ws, size_t ws_size,
                              hipStream_t stream) {
    const void* qin = d_in[0];
    const void* kin = d_in[1];
    const void* vin = d_in[2];
    // d_in[3] = mask: causal, applied analytically
    const void* Wq = d_in[4];
    const void* bq = d_in[5];
    const void* Wk = d_in[6];
    const void* bk = d_in[7];
    const void* Wv = d_in[8];
    const void* bv = d_in[9];
    const void* Wo = d_in[10];
    const void* bo = d_in[11];

    char* ws = (char*)d_ws;
    size_t off = 0;
    auto alloc = [&](size_t bytes) {
        char* p = ws + off;
        off += ((bytes + 255) & ~(size_t)255);
        return (void*)p;
    };
    bf16* qt   = (bf16*)alloc((size_t)B_ * H_ * S_ * DQK_ * 2);   // 16.8 MB
    bf16* ktp  = (bf16*)alloc((size_t)B_ * H_ * S_ * DQK_ * 2);   // 16.8 MB
    bf16* vtp  = (bf16*)alloc((size_t)B_ * H_ * DVP_ * S_ * 2);   // 12.6 MB
    bf16* ob   = (bf16*)alloc((size_t)B_ * S_ * KP_ * 2);         // 11.3 MB
    bf16* wT   = (bf16*)alloc((size_t)NVP_ * DMODEL_ * 2);        // 11.5 MB
    bf16* proj = (bf16*)alloc((size_t)B_ * S_ * NV_ * 2);         // 22.3 MB
    bf16* scr  = (bf16*)alloc((size_t)B_ * S_ * DMODEL_ * 2);     // 16.8 MB (norm staging)
    float* bqf = (float*)alloc(DMODEL_ * 4);
    float* bkf = (float*)alloc(DMODEL_ * 4);
    float* bvf = (float*)alloc(NV_ * 4);
    float* bof = (float*)alloc(DMODEL_ * 4);
    int*  flag = (int*)alloc(256);

    dim3 tb(32, 8);
    auto nblk = [](long n8) { return (int)((n8 + 255) / 256); };

    // 0. detect input dtype (1 = bf16-packed, 0 = fp32)
    detect_dtype<<<1, 256, 0, stream>>>((const unsigned int*)qin, flag);

    // biases -> fp32 (single launch)
    norm_bias4<<<(3 * DMODEL_ + NV_ + 255) / 256, 256, 0, stream>>>(
        bq, bk, bv, bo, bqf, bkf, bvf, bof, flag);

    long n8_w = (long)DMODEL_ * DMODEL_ / 8;
    long n8_x = (long)B_ * S_ * DMODEL_ / 8;

    // Q path
    norm_mat<<<nblk(n8_w), 256, 0, stream>>>(Wq, scr, flag, n8_w);
    transpose_pad<<<dim3(DMODEL_ / 32, DMODEL_ / 32), tb, 0, stream>>>(scr, wT, DMODEL_, DMODEL_, DMODEL_, DMODEL_);
    norm_mat<<<nblk(n8_x), 256, 0, stream>>>(qin, scr, flag, n8_x);
    gemm_bt<<<dim3(32, 16), 256, 0, stream>>>(scr, wT, bqf, proj, nullptr, nullptr, 4096, 2048, 2048, 2048, 2048);
    rope_tr<<<(B_ * S_ * H_ * 64) / 256, 256, 0, stream>>>(proj, qt);

    // K path
    norm_mat<<<nblk(n8_w), 256, 0, stream>>>(Wk, scr, flag, n8_w);
    transpose_pad<<<dim3(DMODEL_ / 32, DMODEL_ / 32), tb, 0, stream>>>(scr, wT, DMODEL_, DMODEL_, DMODEL_, DMODEL_);
    norm_mat<<<nblk(n8_x), 256, 0, stream>>>(kin, scr, flag, n8_x);
    gemm_bt<<<dim3(32, 16), 256, 0, stream>>>(scr, wT, bkf, proj, nullptr, nullptr, 4096, 2048, 2048, 2048, 2048);
    rope_tr<<<(B_ * S_ * H_ * 64) / 256, 256, 0, stream>>>(proj, ktp);

    // V path
    long n8_wv = (long)DMODEL_ * NV_ / 8;
    norm_mat<<<nblk(n8_wv), 256, 0, stream>>>(Wv, scr, flag, n8_wv);
    transpose_pad<<<dim3(DMODEL_ / 32, NVP_ / 32), tb, 0, stream>>>(scr, wT, DMODEL_, NV_, DMODEL_, NVP_);
    norm_mat<<<nblk(n8_x), 256, 0, stream>>>(vin, scr, flag, n8_x);
    gemm_bt<<<dim3(32, NVP_ / 128), 256, 0, stream>>>(scr, wT, bvf, proj, nullptr, nullptr, 4096, NVP_, 2048, NV_, NV_);
    hipMemsetAsync(vtp, 0, (size_t)B_ * H_ * DVP_ * S_ * sizeof(bf16), stream);
    ones_row<<<(B_ * H_ * S_) / 256, 256, 0, stream>>>(vtp);
    swiglu_tr<<<(B_ * S_ * NKV_) / 256, 256, 0, stream>>>(proj, vtp);

    // attention (ob zero-filled so K-pad cols 1360..1375 are 0)
    hipMemsetAsync(ob, 0, (size_t)B_ * S_ * KP_ * sizeof(bf16), stream);
    attn<<<1024, 256, 0, stream>>>(qt, ktp, vtp, ob);

    // output projection
    long n8_wo = (long)NKV_ * DMODEL_ / 8;
    norm_mat<<<nblk(n8_wo), 256, 0, stream>>>(Wo, scr, flag, n8_wo);
    transpose_pad<<<dim3(KP_ / 32, DMODEL_ / 32), tb, 0, stream>>>(scr, wT, NKV_, DMODEL_, KP_, DMODEL_);
    gemm_bt<<<dim3(32, 16), 256, 0, stream>>>(ob, wT, bof, (bf16*)d_out, (float*)d_out, flag,
                                              4096, 2048, KP_, 2048, 2048);
}